// Round 5
// baseline (732.506 us; speedup 1.0000x reference)
//
#include <hip/hip_runtime.h>
#include <math.h>

#define Bsz  4
#define Tlen 2048
#define Dm   1024
#define Hh   8
#define dh   128
#define Mrows (Bsz * Tlen)   // 8192
#define CH   128             // checkpoint interval for pass 2
#define NCH  (Tlen / CH)     // 16 checkpoint chunks
#define C64  64              // solve chunk
#define NC64 (Tlen / C64)    // 32 solve chunks

typedef __attribute__((ext_vector_type(8))) short  s16x8;
typedef __attribute__((ext_vector_type(4))) float  f32x4;
typedef __attribute__((ext_vector_type(2))) float  f32x2;

__device__ inline unsigned short f2b_rne(float f) {
    unsigned int u = __float_as_uint(f);
    u += 0x7FFFu + ((u >> 16) & 1u);
    return (unsigned short)(u >> 16);
}
__device__ inline float b2f(unsigned short u) {
    return __uint_as_float(((unsigned int)u) << 16);
}

__global__ __launch_bounds__(256) void cvt_f32_bf16(const float* __restrict__ in,
                                                    unsigned short* __restrict__ out)
{
    const size_t i = ((size_t)blockIdx.x * 256 + threadIdx.x) * 4;
    float4 v = *(const float4*)&in[i];
    ushort4 o;
    o.x = f2b_rne(v.x); o.y = f2b_rne(v.y);
    o.z = f2b_rne(v.z); o.w = f2b_rne(v.w);
    *(ushort4*)&out[i] = o;
}

// ---------------------------------------------------------------------------
// bf16 MFMA GEMM: val = sum_k A[m][k]*W[n][k] (+bias)   (unchanged, proven)
// ---------------------------------------------------------------------------
__global__ __launch_bounds__(256) void gemm_bf16(const unsigned short* __restrict__ A,
                                                 const unsigned short* __restrict__ Wt,
                                                 const float* __restrict__ bias,
                                                 float* __restrict__ Yf,
                                                 unsigned short* __restrict__ Y16,
                                                 int mode)
{
    __shared__ __align__(16) unsigned short As[128 * 32];
    __shared__ __align__(16) unsigned short Bs[128 * 32];

    const int tid   = threadIdx.x;
    const int w     = tid >> 6;
    const int lane  = tid & 63;
    const int r4    = lane >> 2;
    const int p4    = lane & 3;
    const int row16 = lane & 15;
    const int quad  = lane >> 4;

    const int m0 = blockIdx.y * 128;
    const int n0 = blockIdx.x * 128;
    const int wm = (w >> 1) * 64;
    const int wn = (w & 1) * 64;

    f32x4 acc[4][4];
#pragma unroll
    for (int i = 0; i < 4; ++i)
#pragma unroll
        for (int j = 0; j < 4; ++j)
            acc[i][j] = (f32x4){0.f, 0.f, 0.f, 0.f};

    for (int k0 = 0; k0 < 1024; k0 += 32) {
        __syncthreads();
#pragma unroll
        for (int c = 0; c < 2; ++c) {
            const int ml  = w * 32 + c * 16 + r4;
            const int swz = (ml >> 1) & 3;
            const unsigned short* ga = A  + (size_t)(m0 + ml) * 1024 + k0 + ((p4 ^ swz) << 3);
            const unsigned short* gb = Wt + (size_t)(n0 + ml) * 1024 + k0 + ((p4 ^ swz) << 3);
            __builtin_amdgcn_global_load_lds(
                (const __attribute__((address_space(1))) void*)ga,
                (__attribute__((address_space(3))) void*)&As[(w * 32 + c * 16) * 32], 16, 0, 0);
            __builtin_amdgcn_global_load_lds(
                (const __attribute__((address_space(1))) void*)gb,
                (__attribute__((address_space(3))) void*)&Bs[(w * 32 + c * 16) * 32], 16, 0, 0);
        }
        __syncthreads();

        s16x8 af[4], bf[4];
#pragma unroll
        for (int bm = 0; bm < 4; ++bm) {
            const int ml  = wm + bm * 16 + row16;
            const int pos = quad ^ ((ml >> 1) & 3);
            af[bm] = *(const s16x8*)&As[ml * 32 + pos * 8];
        }
#pragma unroll
        for (int bn = 0; bn < 4; ++bn) {
            const int nl  = wn + bn * 16 + row16;
            const int pos = quad ^ ((nl >> 1) & 3);
            bf[bn] = *(const s16x8*)&Bs[nl * 32 + pos * 8];
        }
#pragma unroll
        for (int bm = 0; bm < 4; ++bm)
#pragma unroll
            for (int bn = 0; bn < 4; ++bn)
                acc[bm][bn] = __builtin_amdgcn_mfma_f32_16x16x32_bf16(af[bm], bf[bn], acc[bm][bn], 0, 0, 0);
    }

#pragma unroll
    for (int bm = 0; bm < 4; ++bm) {
        const int row = m0 + wm + bm * 16 + quad * 4;
#pragma unroll
        for (int bn = 0; bn < 4; ++bn) {
            const int col = n0 + wn + bn * 16 + row16;
            const float bb = bias ? bias[col] : 0.f;
#pragma unroll
            for (int r = 0; r < 4; ++r) {
                float val = acc[bm][bn][r] + bb;
                if (mode == 1) val = 1.f / (1.f + __expf(-val));
                if (mode == 2) Y16[(size_t)(row + r) * 1024 + col] = f2b_rne(val);
                else           Yf [(size_t)(row + r) * 1024 + col] = val;
            }
        }
    }
}

// ---------------------------------------------------------------------------
// L2-normalize K,V rows in place; write normalized K as bf16 (K16) and the
// bf16 residual (K16lo = bf16(k - bf16(k))) for precision-compensated Grams.
// ---------------------------------------------------------------------------
__global__ __launch_bounds__(256) void l2norm_rows(float* __restrict__ Kb,
                                                   float* __restrict__ Vb,
                                                   unsigned short* __restrict__ K16,
                                                   unsigned short* __restrict__ K16lo)
{
    const int gtid = blockIdx.x * 256 + threadIdx.x;
    const int row  = gtid >> 6;
    const int lane = threadIdx.x & 63;
    const size_t base = (size_t)row * dh + lane * 2;

    float2 k2 = *(float2*)&Kb[base];
    float2 v2 = *(float2*)&Vb[base];
    float sk = k2.x * k2.x + k2.y * k2.y;
    float sv = v2.x * v2.x + v2.y * v2.y;
#pragma unroll
    for (int off = 1; off < 64; off <<= 1) {
        sk += __shfl_xor(sk, off);
        sv += __shfl_xor(sv, off);
    }
    const float rk = 1.f / fmaxf(sqrtf(sk), 1e-12f);
    const float rv = 1.f / fmaxf(sqrtf(sv), 1e-12f);
    k2.x *= rk; k2.y *= rk;
    v2.x *= rv; v2.y *= rv;
    *(float2*)&Kb[base] = k2;
    *(float2*)&Vb[base] = v2;
    const unsigned short hx = f2b_rne(k2.x), hy = f2b_rne(k2.y);
    ((unsigned int*)K16)[base >> 1] = (unsigned int)hx | ((unsigned int)hy << 16);
    const unsigned short lx = f2b_rne(k2.x - b2f(hx));
    const unsigned short ly = f2b_rne(k2.y - b2f(hy));
    ((unsigned int*)K16lo)[base >> 1] = (unsigned int)lx | ((unsigned int)ly << 16);
}

// ---------------------------------------------------------------------------
// gram_kt: per (bh, c64-chunk): G = K_c K_c^T (f32, lo-compensated, MFMA) and
// K^T tiles (bf16 hi/lo) for the solve kernel's W-update GEMM.
// Grid: 32*32 = 1024 blocks, 256 threads. Fully parallel.
// ---------------------------------------------------------------------------
__global__ __launch_bounds__(256) void gram_kt(const unsigned short* __restrict__ K16,
                                               const unsigned short* __restrict__ K16lo,
                                               float* __restrict__ Gf,
                                               unsigned short* __restrict__ KThi,
                                               unsigned short* __restrict__ KTlo)
{
    __shared__ __align__(16) unsigned short Kp[2][64 * 136];   // [hi/lo][t][j] pad-136

    const int blk = blockIdx.x;
    const int c   = blk & 31;
    const int bh  = blk >> 5;
    const int b   = bh >> 3, h = bh & 7;
    const int tid = threadIdx.x;

    // stage K rows (plain, padded)
    {
        const int row = tid >> 2, seg = (tid & 3) * 32;
        const size_t gsrc = ((size_t)(b * Tlen + c * C64 + row)) * Dm + h * dh + seg;
        const s16x8* ph = (const s16x8*)&K16[gsrc];
        const s16x8* pl = (const s16x8*)&K16lo[gsrc];
#pragma unroll
        for (int q = 0; q < 4; ++q) {
            *(s16x8*)&Kp[0][row * 136 + seg + q * 8] = ph[q];
            *(s16x8*)&Kp[1][row * 136 + seg + q * 8] = pl[q];
        }
    }
    __syncthreads();

    const int w     = tid >> 6;
    const int lane  = tid & 63;
    const int row16 = lane & 15;
    const int quad  = lane >> 4;
    const int sh = (w >> 1) * 32;
    const int th = (w & 1) * 32;

    f32x4 ag[2][2];
#pragma unroll
    for (int i = 0; i < 2; ++i)
#pragma unroll
        for (int j = 0; j < 2; ++j)
            ag[2 > i ? i : i][j] = (f32x4){0.f, 0.f, 0.f, 0.f};

    // 3 passes: hi*hi + hi*lo + lo*hi
#pragma unroll
    for (int pass = 0; pass < 3; ++pass) {
        const int pa = (pass == 2) ? 1 : 0;
        const int pb = (pass == 1) ? 1 : 0;
#pragma unroll
        for (int k0 = 0; k0 < 128; k0 += 32) {
            s16x8 af[2], bf[2];
#pragma unroll
            for (int bm = 0; bm < 2; ++bm) {
                const int ml = sh + bm * 16 + row16;
                af[bm] = *(const s16x8*)&Kp[pa][ml * 136 + k0 + quad * 8];
            }
#pragma unroll
            for (int bn = 0; bn < 2; ++bn) {
                const int nl = th + bn * 16 + row16;
                bf[bn] = *(const s16x8*)&Kp[pb][nl * 136 + k0 + quad * 8];
            }
#pragma unroll
            for (int bm = 0; bm < 2; ++bm)
#pragma unroll
                for (int bn = 0; bn < 2; ++bn)
                    ag[bm][bn] = __builtin_amdgcn_mfma_f32_16x16x32_bf16(af[bm], bf[bn], ag[bm][bn], 0, 0, 0);
        }
    }

    // write G f32 [bh][c][s][t]
    float* gout = Gf + ((size_t)(bh * 32 + c)) * 4096;
#pragma unroll
    for (int bm = 0; bm < 2; ++bm)
#pragma unroll
        for (int bn = 0; bn < 2; ++bn) {
            const int t = th + bn * 16 + row16;
#pragma unroll
            for (int r = 0; r < 4; ++r) {
                const int s = sh + bm * 16 + quad * 4 + r;
                gout[s * 64 + t] = ag[bm][bn][r];
            }
        }

    // K^T extraction: KT[bh][c][j][t]
    {
        const int j   = tid >> 1;
        const int th2 = (tid & 1) * 32;
        unsigned int pk[16];
#pragma unroll
        for (int hl = 0; hl < 2; ++hl) {
#pragma unroll
            for (int p = 0; p < 16; ++p) {
                const unsigned short e0 = Kp[hl][(th2 + 2 * p) * 136 + j];
                const unsigned short e1 = Kp[hl][(th2 + 2 * p + 1) * 136 + j];
                pk[p] = (unsigned int)e0 | ((unsigned int)e1 << 16);
            }
            unsigned short* dst = (hl ? KTlo : KThi) +
                ((size_t)(bh * 32 + c) * 128 + j) * 64 + th2;
#pragma unroll
            for (int q = 0; q < 4; ++q)
                *(uint4*)&dst[q * 8] = *(uint4*)&pk[q * 4];
        }
    }
}

// ---------------------------------------------------------------------------
// solve_coef: the only serial kernel. One block per bh (32 blocks, 4 waves).
// Per 64-chunk: dump W (bf16)->LDS; A0 = W*K_c^T (MFMA); 64-step forward
// substitution (lane = i, packed-f32 FMAs, G broadcast from LDS);
// W += U*K_c (MFMA, hi+lo compensated). Emits Ut (bf16 [bh][i][t]) and
// Wcp (bf16, every 128 steps) in the formats chunk_o already consumes.
// Dynamic LDS: 96 KiB.
// ---------------------------------------------------------------------------
__global__ __launch_bounds__(256) void solve_coef(const unsigned short* __restrict__ K16,
                                                  const float* __restrict__ Vb,
                                                  const float* __restrict__ LRb,
                                                  const float* __restrict__ Gf,
                                                  const unsigned short* __restrict__ KThi,
                                                  const unsigned short* __restrict__ KTlo,
                                                  unsigned short* __restrict__ Ut,
                                                  unsigned short* __restrict__ Wcp)
{
    extern __shared__ __align__(16) char smem[];
    unsigned short* Khs = (unsigned short*)smem;              // [4][64][32]  16K  (A0 B-op)
    unsigned short* Ws  = (unsigned short*)(smem + 16384);    // P1: Whi slabs [4][128][32] 32K; P2/P3: KT slabs
    float*          Gs  = (float*)(smem + 49152);             // [64][64] f32 16K
    unsigned short* Uhi = (unsigned short*)(smem + 65536);    // [128][64] XOR 16K
    unsigned short* Ulo = (unsigned short*)(smem + 81920);    // [128][64] XOR 16K; doubles as A0 [64][128] XOR

    const int bh = blockIdx.x;
    const int b  = bh >> 3, h = bh & 7;
    const int tid   = threadIdx.x;
    const int w     = tid >> 6;
    const int lane  = tid & 63;
    const int p4    = lane & 3;
    const int row16 = lane & 15;
    const int quad  = lane >> 4;
    const int wm = (w >> 1) * 64;     // W-tile i-half
    const int wn = (w & 1) * 64;      // W-tile j-half
    const int ih  = (w >> 1) * 64;    // A0 i-half
    const int th2 = (w & 1) * 32;     // A0 t-half

    f32x4 Wa[4][4];
#pragma unroll
    for (int i = 0; i < 4; ++i)
#pragma unroll
        for (int j = 0; j < 4; ++j)
            Wa[i][j] = (f32x4){0.f, 0.f, 0.f, 0.f};

    const int ilane = w * 64 + lane;  // solve row (waves 0,1)
    f32x2 r2[32];

#pragma unroll 1
    for (int c = 0; c < NC64; ++c) {
        const int t0g = c * C64;

        // ---- P0: issue Khi + G stages; dump W -> Ws (bf16) --------------
#pragma unroll
        for (int c4 = 0; c4 < 4; ++c4) {
            const int rr = c4 * 16 + (lane >> 2);
            const unsigned short* ga = K16 + ((size_t)(b * Tlen + t0g + rr)) * Dm + h * dh
                                       + w * 32 + ((p4 ^ ((rr >> 1) & 3)) << 3);
            __builtin_amdgcn_global_load_lds(
                (const __attribute__((address_space(1))) void*)ga,
                (__attribute__((address_space(3))) void*)((char*)Khs + w * 4096 + c4 * 1024 + lane * 16),
                16, 0, 0);
        }
        {
            const size_t gbase = (size_t)(bh * 32 + c) * 4096;
#pragma unroll
            for (int c4 = 0; c4 < 4; ++c4) {
                const float* gg = Gf + gbase + w * 1024 + c4 * 256 + lane * 4;
                __builtin_amdgcn_global_load_lds(
                    (const __attribute__((address_space(1))) void*)gg,
                    (__attribute__((address_space(3))) void*)((char*)Gs + (w * 1024 + c4 * 256 + lane * 4) * 4),
                    16, 0, 0);
            }
        }
#pragma unroll
        for (int bm = 0; bm < 4; ++bm)
#pragma unroll
            for (int bn = 0; bn < 4; ++bn) {
                const int j  = wn + bn * 16 + row16;
                const int sl = j >> 5, jj = j & 31;
#pragma unroll
                for (int r = 0; r < 4; ++r) {
                    const int i = wm + bm * 16 + quad * 4 + r;
                    Ws[sl * 4096 + i * 32 + (((jj >> 3) ^ ((i >> 1) & 3)) << 3) + (j & 7)] =
                        f2b_rne(Wa[bm][bn][r]);
                }
            }
        __syncthreads();

        // ---- P1: A0 = W * K_c^T (MFMA) -> A0 LDS (bf16, [t][i] XOR) -----
        {
            f32x4 aA[4][2];
#pragma unroll
            for (int i = 0; i < 4; ++i)
#pragma unroll
                for (int j = 0; j < 2; ++j)
                    aA[i][j] = (f32x4){0.f, 0.f, 0.f, 0.f};
#pragma unroll
            for (int k0s = 0; k0s < 4; ++k0s) {
                s16x8 af[4], bf[2];
#pragma unroll
                for (int bm = 0; bm < 4; ++bm) {
                    const int ml = ih + bm * 16 + row16;
                    af[bm] = *(const s16x8*)&Ws[k0s * 4096 + ml * 32 + ((quad ^ ((ml >> 1) & 3)) << 3)];
                }
#pragma unroll
                for (int bn = 0; bn < 2; ++bn) {
                    const int nl = th2 + bn * 16 + row16;
                    bf[bn] = *(const s16x8*)&Khs[k0s * 2048 + nl * 32 + ((quad ^ ((nl >> 1) & 3)) << 3)];
                }
#pragma unroll
                for (int bm = 0; bm < 4; ++bm)
#pragma unroll
                    for (int bn = 0; bn < 2; ++bn)
                        aA[bm][bn] = __builtin_amdgcn_mfma_f32_16x16x32_bf16(af[bm], bf[bn], aA[bm][bn], 0, 0, 0);
            }
#pragma unroll
            for (int bm = 0; bm < 4; ++bm)
#pragma unroll
                for (int bn = 0; bn < 2; ++bn) {
                    const int t = th2 + bn * 16 + row16;
#pragma unroll
                    for (int r = 0; r < 4; ++r) {
                        const int i = ih + bm * 16 + quad * 4 + r;
                        Ulo[t * 128 + (((i >> 3) ^ (t & 7)) << 3) + (i & 7)] = f2b_rne(aA[bm][bn][r]);
                    }
                }
        }
        // checkpoint copy (W at chunk start) every 2nd chunk: Ws -> Wcp
        if ((c & 1) == 0) {
            const int i2 = tid >> 1, half = tid & 1;
            unsigned short* dstrow = Wcp + ((size_t)(bh * NCH + (c >> 1)) * 128 + i2) * 128;
#pragma unroll
            for (int sl = 0; sl < 4; ++sl)
#pragma unroll
                for (int gq = 0; gq < 2; ++gq) {
                    const int gg = half * 2 + gq;
                    s16x8 v = *(const s16x8*)&Ws[sl * 4096 + i2 * 32 + ((gg ^ ((i2 >> 1) & 3)) << 3)];
                    *(s16x8*)&dstrow[sl * 32 + gg * 8] = v;
                }
        }
        __syncthreads();

        // ---- P2: waves 2,3: stage KT slabs into Ws; waves 0,1: solve ----
        if (w >= 2) {
            const int base2 = (w - 2) * 2;   // wave2: bufs 0,1 (hi); wave3: bufs 2,3 (lo)
#pragma unroll
            for (int bb = 0; bb < 2; ++bb) {
                const int buf = base2 + bb;
                const int st  = buf & 1;
                const unsigned short* src = (buf < 2) ? KThi : KTlo;
#pragma unroll
                for (int c8 = 0; c8 < 8; ++c8) {
                    const int jj = c8 * 16 + (lane >> 2);
                    const unsigned short* ga = src + ((size_t)(bh * 32 + c) * 128 + jj) * 64
                                               + st * 32 + ((p4 ^ ((jj >> 1) & 3)) << 3);
                    __builtin_amdgcn_global_load_lds(
                        (const __attribute__((address_space(1))) void*)ga,
                        (__attribute__((address_space(3))) void*)((char*)Ws + buf * 8192 + c8 * 1024 + lane * 16),
                        16, 0, 0);
                }
            }
        } else {
            const int i = ilane;
            const float* vp  = Vb  + ((size_t)(b * Tlen + t0g)) * Dm + h * dh + i;
            const float* lrp = LRb + ((size_t)(b * Tlen + t0g)) * Dm + h * dh + i;
            // r-init: r[t] = v[t] - A0[t][i]
#pragma unroll
            for (int p = 0; p < 32; ++p) {
                const int ta = 2 * p, tb = 2 * p + 1;
                const float a0a = b2f(Ulo[ta * 128 + (((i >> 3) ^ (ta & 7)) << 3) + (i & 7)]);
                const float a0b = b2f(Ulo[tb * 128 + (((i >> 3) ^ (tb & 7)) << 3) + (i & 7)]);
                r2[p].x = vp[(size_t)ta * Dm] - a0a;
                r2[p].y = vp[(size_t)tb * Dm] - a0b;
            }
            float lv[8], o8[8];
#pragma unroll
            for (int s = 0; s < C64; ++s) {
                if ((s & 7) == 0) {
#pragma unroll
                    for (int u = 0; u < 8; ++u)
                        lv[u] = lrp[(size_t)(s + u) * Dm];
                }
                const float rs = (s & 1) ? r2[s >> 1].y : r2[s >> 1].x;
                const float cf = lv[s & 7] * rs;
                o8[s & 7] = cf;
                const f32x2 cf2 = (f32x2){cf, cf};
#pragma unroll
                for (int p = (s + 1) >> 1; p < 32; ++p) {
                    const f32x2 gg = *(const f32x2*)&Gs[s * 64 + 2 * p];
                    r2[p] -= cf2 * gg;
                }
                if ((s & 7) == 7) {
                    const int t0 = s - 7;
                    unsigned int phi[4], plo[4];
#pragma unroll
                    for (int q = 0; q < 4; ++q) {
                        const unsigned short h0 = f2b_rne(o8[2 * q]);
                        const unsigned short h1 = f2b_rne(o8[2 * q + 1]);
                        const unsigned short l0 = f2b_rne(o8[2 * q] - b2f(h0));
                        const unsigned short l1 = f2b_rne(o8[2 * q + 1] - b2f(h1));
                        phi[q] = (unsigned int)h0 | ((unsigned int)h1 << 16);
                        plo[q] = (unsigned int)l0 | ((unsigned int)l1 << 16);
                    }
                    const int lg  = (t0 >> 3) ^ (i & 7);
                    *(uint4*)&Uhi[i * 64 + (lg << 3)] = *(uint4*)phi;
                    *(uint4*)&Ulo[i * 64 + (lg << 3)] = *(uint4*)plo;
                    *(uint4*)&Ut[(size_t)(bh * 128 + i) * Tlen + t0g + t0] = *(uint4*)phi;
                }
            }
        }
        __syncthreads();

        // ---- P3: W += Uhi*KThi + Ulo*KThi + Uhi*KTlo (MFMA) -------------
#pragma unroll
        for (int pass = 0; pass < 3; ++pass) {
            const unsigned short* Ua = (pass == 1) ? Ulo : Uhi;
            const int bufbase = (pass == 2) ? 2 : 0;
#pragma unroll
            for (int st = 0; st < 2; ++st) {
                s16x8 af[4], bf[4];
#pragma unroll
                for (int bm = 0; bm < 4; ++bm) {
                    const int ml = wm + bm * 16 + row16;
                    af[bm] = *(const s16x8*)&Ua[ml * 64 + (((st * 4 + quad) ^ (ml & 7)) << 3)];
                }
#pragma unroll
                for (int bn = 0; bn < 4; ++bn) {
                    const int nl = wn + bn * 16 + row16;
                    bf[bn] = *(const s16x8*)&Ws[(bufbase + st) * 4096 + nl * 32 + ((quad ^ ((nl >> 1) & 3)) << 3)];
                }
#pragma unroll
                for (int bm = 0; bm < 4; ++bm)
#pragma unroll
                    for (int bn = 0; bn < 4; ++bn)
                        Wa[bm][bn] = __builtin_amdgcn_mfma_f32_16x16x32_bf16(af[bm], bf[bn], Wa[bm][bn], 0, 0, 0);
            }
        }
        __syncthreads();
    }
}

// ---------------------------------------------------------------------------
// Pass 2: per 128-chunk output via MFMA.  (unchanged, proven)
// ---------------------------------------------------------------------------
__global__ __launch_bounds__(256) void chunk_o(const unsigned short* __restrict__ Q16,
                                               const unsigned short* __restrict__ K16,
                                               const unsigned short* __restrict__ Ut,
                                               const unsigned short* __restrict__ Wcp,
                                               unsigned short* __restrict__ Obb)
{
    __shared__ __align__(16) unsigned short As[128 * 32];
    __shared__ __align__(16) unsigned short Bs[128 * 32];
    __shared__ __align__(16) unsigned short Sb[128 * 136];   // +8 pad

    const int blk = blockIdx.x;
    const int c   = blk & (NCH - 1);
    const int bh  = blk >> 4;
    const int b   = bh >> 3, h = bh & 7;

    const int tid   = threadIdx.x;
    const int w     = tid >> 6;
    const int lane  = tid & 63;
    const int r4    = lane >> 2;
    const int p4    = lane & 3;
    const int row16 = lane & 15;
    const int quad  = lane >> 4;
    const int wm = (w >> 1) * 64;
    const int wn = (w & 1) * 64;

    const size_t qkbase = (size_t)b * Tlen * Dm + (size_t)(c * CH) * Dm + (size_t)h * dh;
    const size_t ubase  = (size_t)bh * dh * Tlen + (size_t)c * CH;
    const size_t wbase  = ((size_t)bh * NCH + c) * dh * dh;

    f32x4 acc[4][4];
#pragma unroll
    for (int i = 0; i < 4; ++i)
#pragma unroll
        for (int j = 0; j < 4; ++j)
            acc[i][j] = (f32x4){0.f, 0.f, 0.f, 0.f};

    for (int k0 = 0; k0 < 128; k0 += 32) {
        __syncthreads();
#pragma unroll
        for (int cc = 0; cc < 2; ++cc) {
            const int ml  = w * 32 + cc * 16 + r4;
            const int swz = (ml >> 1) & 3;
            const unsigned short* ga = Q16 + qkbase + (size_t)ml * Dm + k0 + ((p4 ^ swz) << 3);
            const unsigned short* gb = K16 + qkbase + (size_t)ml * Dm + k0 + ((p4 ^ swz) << 3);
            __builtin_amdgcn_global_load_lds(
                (const __attribute__((address_space(1))) void*)ga,
                (__attribute__((address_space(3))) void*)&As[(w * 32 + cc * 16) * 32], 16, 0, 0);
            __builtin_amdgcn_global_load_lds(
                (const __attribute__((address_space(1))) void*)gb,
                (__attribute__((address_space(3))) void*)&Bs[(w * 32 + cc * 16) * 32], 16, 0, 0);
        }
        __syncthreads();

        s16x8 af[4], bf[4];
#pragma unroll
        for (int bm = 0; bm < 4; ++bm) {
            const int ml  = wm + bm * 16 + row16;
            const int pos = quad ^ ((ml >> 1) & 3);
            af[bm] = *(const s16x8*)&As[ml * 32 + pos * 8];
        }
#pragma unroll
        for (int bn = 0; bn < 4; ++bn) {
            const int nl  = wn + bn * 16 + row16;
            const int pos = quad ^ ((nl >> 1) & 3);
            bf[bn] = *(const s16x8*)&Bs[nl * 32 + pos * 8];
        }
#pragma unroll
        for (int bm = 0; bm < 4; ++bm)
#pragma unroll
            for (int bn = 0; bn < 4; ++bn)
                acc[bm][bn] = __builtin_amdgcn_mfma_f32_16x16x32_bf16(af[bm], bf[bn], acc[bm][bn], 0, 0, 0);
    }

#pragma unroll
    for (int bm = 0; bm < 4; ++bm) {
#pragma unroll
        for (int bn = 0; bn < 4; ++bn) {
            const int s_loc = wn + bn * 16 + row16;
#pragma unroll
            for (int r = 0; r < 4; ++r) {
                const int t_loc = wm + bm * 16 + quad * 4 + r;
                const float val = (s_loc <= t_loc) ? acc[bm][bn][r] : 0.f;
                Sb[t_loc * 136 + s_loc] = f2b_rne(val);
            }
            acc[bm][bn] = (f32x4){0.f, 0.f, 0.f, 0.f};
        }
    }

    for (int k0 = 0; k0 < 128; k0 += 32) {
        __syncthreads();
#pragma unroll
        for (int cc = 0; cc < 2; ++cc) {
            const int nl  = w * 32 + cc * 16 + r4;
            const int swz = (nl >> 1) & 3;
            const unsigned short* gb = Ut + ubase + (size_t)nl * Tlen + k0 + ((p4 ^ swz) << 3);
            __builtin_amdgcn_global_load_lds(
                (const __attribute__((address_space(1))) void*)gb,
                (__attribute__((address_space(3))) void*)&Bs[(w * 32 + cc * 16) * 32], 16, 0, 0);
        }
        __syncthreads();

        s16x8 af[4], bf[4];
#pragma unroll
        for (int bm = 0; bm < 4; ++bm) {
            const int ml = wm + bm * 16 + row16;
            af[bm] = *(const s16x8*)&Sb[ml * 136 + k0 + quad * 8];
        }
#pragma unroll
        for (int bn = 0; bn < 4; ++bn) {
            const int nl  = wn + bn * 16 + row16;
            const int pos = quad ^ ((nl >> 1) & 3);
            bf[bn] = *(const s16x8*)&Bs[nl * 32 + pos * 8];
        }
#pragma unroll
        for (int bm = 0; bm < 4; ++bm)
#pragma unroll
            for (int bn = 0; bn < 4; ++bn)
                acc[bm][bn] = __builtin_amdgcn_mfma_f32_16x16x32_bf16(af[bm], bf[bn], acc[bm][bn], 0, 0, 0);
    }

    for (int k0 = 0; k0 < 128; k0 += 32) {
        __syncthreads();
#pragma unroll
        for (int cc = 0; cc < 2; ++cc) {
            const int ml  = w * 32 + cc * 16 + r4;
            const int swz = (ml >> 1) & 3;
            const unsigned short* ga = Q16 + qkbase + (size_t)ml * Dm + k0 + ((p4 ^ swz) << 3);
            const unsigned short* gb = Wcp + wbase + (size_t)ml * dh + k0 + ((p4 ^ swz) << 3);
            __builtin_amdgcn_global_load_lds(
                (const __attribute__((address_space(1))) void*)ga,
                (__attribute__((address_space(3))) void*)&As[(w * 32 + cc * 16) * 32], 16, 0, 0);
            __builtin_amdgcn_global_load_lds(
                (const __attribute__((address_space(1))) void*)gb,
                (__attribute__((address_space(3))) void*)&Bs[(w * 32 + cc * 16) * 32], 16, 0, 0);
        }
        __syncthreads();

        s16x8 af[4], bf[4];
#pragma unroll
        for (int bm = 0; bm < 4; ++bm) {
            const int ml  = wm + bm * 16 + row16;
            const int pos = quad ^ ((ml >> 1) & 3);
            af[bm] = *(const s16x8*)&As[ml * 32 + pos * 8];
        }
#pragma unroll
        for (int bn = 0; bn < 4; ++bn) {
            const int nl  = wn + bn * 16 + row16;
            const int pos = quad ^ ((nl >> 1) & 3);
            bf[bn] = *(const s16x8*)&Bs[nl * 32 + pos * 8];
        }
#pragma unroll
        for (int bm = 0; bm < 4; ++bm)
#pragma unroll
            for (int bn = 0; bn < 4; ++bn)
                acc[bm][bn] = __builtin_amdgcn_mfma_f32_16x16x32_bf16(af[bm], bf[bn], acc[bm][bn], 0, 0, 0);
    }

#pragma unroll
    for (int bm = 0; bm < 4; ++bm) {
#pragma unroll
        for (int bn = 0; bn < 4; ++bn) {
            const int i_loc = wn + bn * 16 + row16;
#pragma unroll
            for (int r = 0; r < 4; ++r) {
                const int t_loc = wm + bm * 16 + quad * 4 + r;
                Obb[qkbase + (size_t)t_loc * Dm + i_loc] = f2b_rne(acc[bm][bn][r]);
            }
        }
    }
}

// ---------------------------------------------------------------------------
extern "C" void kernel_launch(void* const* d_in, const int* in_sizes, int n_in,
                              void* d_out, int out_size, void* d_ws, size_t ws_size,
                              hipStream_t stream)
{
    const float* x    = (const float*)d_in[0];
    const float* Wq   = (const float*)d_in[1];
    const float* Wk   = (const float*)d_in[2];
    const float* Wv   = (const float*)d_in[3];
    const float* Wo   = (const float*)d_in[4];
    const float* Wlr  = (const float*)d_in[5];
    const float* b_lr = (const float*)d_in[6];

    float* ws = (float*)d_ws;
    const size_t S  = (size_t)Mrows * Dm;    // 8388608
    const size_t SW = (size_t)Dm * Dm;       // 1048576
    float* Kb  = ws;
    float* Vb  = ws + S;
    float* LRb = ws + 2 * S;
    unsigned short* xb   = (unsigned short*)(ws + 3 * S);  // S bf16
    unsigned short* Wcp  = xb;                             // alias: xb dead before solve
    unsigned short* Q16  = xb + S;
    unsigned short* K16  = Q16 + S;
    unsigned short* Ut   = K16 + S;
    unsigned short* Obb  = Ut + S;
    unsigned short* Wqb  = Obb + S;
    unsigned short* Wkb  = Wqb + SW;
    unsigned short* Wvb  = Wkb + SW;
    unsigned short* Wlrb = Wvb + SW;
    unsigned short* Wob  = Wlrb + SW;
    // lifetime-disjoint aliases for the new pipeline:
    unsigned short* K16lo = Ut;              // l2norm -> gram window (Ut written later by solve)
    float*          Gf    = (float*)Obb;     // gram -> solve window (Obb written later by chunk_o)
    unsigned short* KThi  = (unsigned short*)Kb;  // gram -> solve window (Kb f32 dead after l2norm)
    unsigned short* KTlo  = KThi + S;        // KThi+KTlo = exactly |Kb|

    static int attr_done = 0;
    if (!attr_done) {
        (void)hipFuncSetAttribute((const void*)solve_coef,
                                  hipFuncAttributeMaxDynamicSharedMemorySize, 98304);
        attr_done = 1;
    }

    cvt_f32_bf16<<<S / 1024, 256, 0, stream>>>(x, xb);
    cvt_f32_bf16<<<SW / 1024, 256, 0, stream>>>(Wq, Wqb);
    cvt_f32_bf16<<<SW / 1024, 256, 0, stream>>>(Wk, Wkb);
    cvt_f32_bf16<<<SW / 1024, 256, 0, stream>>>(Wv, Wvb);
    cvt_f32_bf16<<<SW / 1024, 256, 0, stream>>>(Wlr, Wlrb);
    cvt_f32_bf16<<<SW / 1024, 256, 0, stream>>>(Wo, Wob);

    dim3 gg(Dm / 128, Mrows / 128);
    gemm_bf16<<<gg, 256, 0, stream>>>(xb, Wqb, nullptr, nullptr, Q16, 2);
    gemm_bf16<<<gg, 256, 0, stream>>>(xb, Wkb, nullptr, Kb, nullptr, 0);
    gemm_bf16<<<gg, 256, 0, stream>>>(xb, Wvb, nullptr, Vb, nullptr, 0);
    gemm_bf16<<<gg, 256, 0, stream>>>(xb, Wlrb, b_lr, LRb, nullptr, 1);

    l2norm_rows<<<(Bsz * Tlen * Hh) / 4, 256, 0, stream>>>(Kb, Vb, K16, K16lo);

    gram_kt<<<32 * 32, 256, 0, stream>>>(K16, K16lo, Gf, KThi, KTlo);

    solve_coef<<<32, 256, 98304, stream>>>(K16, Vb, LRb, Gf, KThi, KTlo, Ut, Wcp);

    chunk_o<<<Bsz * Hh * NCH, 256, 0, stream>>>(Q16, K16, Ut, Wcp, Obb);

    gemm_bf16<<<gg, 256, 0, stream>>>(Obb, Wob, nullptr, (float*)d_out, nullptr, 0);
}

// Round 7
// 698.434 us; speedup vs baseline: 1.0488x; 1.0488x over previous
//
#include <hip/hip_runtime.h>
#include <math.h>

#define Bsz  4
#define Tlen 2048
#define Dm   1024
#define Hh   8
#define dh   128
#define Mrows (Bsz * Tlen)   // 8192
#define CH   128             // checkpoint interval for pass 2
#define NCH  (Tlen / CH)     // 16 checkpoint chunks
#define C64  64              // solve chunk
#define NC64 (Tlen / C64)    // 32 solve chunks

typedef __attribute__((ext_vector_type(8))) short  s16x8;
typedef __attribute__((ext_vector_type(4))) float  f32x4;
typedef __attribute__((ext_vector_type(2))) float  f32x2;

__device__ inline unsigned short f2b_rne(float f) {
    unsigned int u = __float_as_uint(f);
    u += 0x7FFFu + ((u >> 16) & 1u);
    return (unsigned short)(u >> 16);
}
__device__ inline float b2f(unsigned short u) {
    return __uint_as_float(((unsigned int)u) << 16);
}

__global__ __launch_bounds__(256) void cvt_f32_bf16(const float* __restrict__ in,
                                                    unsigned short* __restrict__ out)
{
    const size_t i = ((size_t)blockIdx.x * 256 + threadIdx.x) * 4;
    float4 v = *(const float4*)&in[i];
    ushort4 o;
    o.x = f2b_rne(v.x); o.y = f2b_rne(v.y);
    o.z = f2b_rne(v.z); o.w = f2b_rne(v.w);
    *(ushort4*)&out[i] = o;
}

// ---------------------------------------------------------------------------
// bf16 MFMA GEMM: val = sum_k A[m][k]*W[n][k] (+bias)   (unchanged, proven)
// ---------------------------------------------------------------------------
__global__ __launch_bounds__(256) void gemm_bf16(const unsigned short* __restrict__ A,
                                                 const unsigned short* __restrict__ Wt,
                                                 const float* __restrict__ bias,
                                                 float* __restrict__ Yf,
                                                 unsigned short* __restrict__ Y16,
                                                 int mode)
{
    __shared__ __align__(16) unsigned short As[128 * 32];
    __shared__ __align__(16) unsigned short Bs[128 * 32];

    const int tid   = threadIdx.x;
    const int w     = tid >> 6;
    const int lane  = tid & 63;
    const int r4    = lane >> 2;
    const int p4    = lane & 3;
    const int row16 = lane & 15;
    const int quad  = lane >> 4;

    const int m0 = blockIdx.y * 128;
    const int n0 = blockIdx.x * 128;
    const int wm = (w >> 1) * 64;
    const int wn = (w & 1) * 64;

    f32x4 acc[4][4];
#pragma unroll
    for (int i = 0; i < 4; ++i)
#pragma unroll
        for (int j = 0; j < 4; ++j)
            acc[i][j] = (f32x4){0.f, 0.f, 0.f, 0.f};

    for (int k0 = 0; k0 < 1024; k0 += 32) {
        __syncthreads();
#pragma unroll
        for (int c = 0; c < 2; ++c) {
            const int ml  = w * 32 + c * 16 + r4;
            const int swz = (ml >> 1) & 3;
            const unsigned short* ga = A  + (size_t)(m0 + ml) * 1024 + k0 + ((p4 ^ swz) << 3);
            const unsigned short* gb = Wt + (size_t)(n0 + ml) * 1024 + k0 + ((p4 ^ swz) << 3);
            __builtin_amdgcn_global_load_lds(
                (const __attribute__((address_space(1))) void*)ga,
                (__attribute__((address_space(3))) void*)&As[(w * 32 + c * 16) * 32], 16, 0, 0);
            __builtin_amdgcn_global_load_lds(
                (const __attribute__((address_space(1))) void*)gb,
                (__attribute__((address_space(3))) void*)&Bs[(w * 32 + c * 16) * 32], 16, 0, 0);
        }
        __syncthreads();

        s16x8 af[4], bf[4];
#pragma unroll
        for (int bm = 0; bm < 4; ++bm) {
            const int ml  = wm + bm * 16 + row16;
            const int pos = quad ^ ((ml >> 1) & 3);
            af[bm] = *(const s16x8*)&As[ml * 32 + pos * 8];
        }
#pragma unroll
        for (int bn = 0; bn < 4; ++bn) {
            const int nl  = wn + bn * 16 + row16;
            const int pos = quad ^ ((nl >> 1) & 3);
            bf[bn] = *(const s16x8*)&Bs[nl * 32 + pos * 8];
        }
#pragma unroll
        for (int bm = 0; bm < 4; ++bm)
#pragma unroll
            for (int bn = 0; bn < 4; ++bn)
                acc[bm][bn] = __builtin_amdgcn_mfma_f32_16x16x32_bf16(af[bm], bf[bn], acc[bm][bn], 0, 0, 0);
    }

#pragma unroll
    for (int bm = 0; bm < 4; ++bm) {
        const int row = m0 + wm + bm * 16 + quad * 4;
#pragma unroll
        for (int bn = 0; bn < 4; ++bn) {
            const int col = n0 + wn + bn * 16 + row16;
            const float bb = bias ? bias[col] : 0.f;
#pragma unroll
            for (int r = 0; r < 4; ++r) {
                float val = acc[bm][bn][r] + bb;
                if (mode == 1) val = 1.f / (1.f + __expf(-val));
                if (mode == 2) Y16[(size_t)(row + r) * 1024 + col] = f2b_rne(val);
                else           Yf [(size_t)(row + r) * 1024 + col] = val;
            }
        }
    }
}

// ---------------------------------------------------------------------------
// L2-normalize K,V rows in place; write normalized K as bf16 (K16) and the
// bf16 residual (K16lo = bf16(k - bf16(k))) for precision-compensated Grams.
// ---------------------------------------------------------------------------
__global__ __launch_bounds__(256) void l2norm_rows(float* __restrict__ Kb,
                                                   float* __restrict__ Vb,
                                                   unsigned short* __restrict__ K16,
                                                   unsigned short* __restrict__ K16lo)
{
    const int gtid = blockIdx.x * 256 + threadIdx.x;
    const int row  = gtid >> 6;
    const int lane = threadIdx.x & 63;
    const size_t base = (size_t)row * dh + lane * 2;

    float2 k2 = *(float2*)&Kb[base];
    float2 v2 = *(float2*)&Vb[base];
    float sk = k2.x * k2.x + k2.y * k2.y;
    float sv = v2.x * v2.x + v2.y * v2.y;
#pragma unroll
    for (int off = 1; off < 64; off <<= 1) {
        sk += __shfl_xor(sk, off);
        sv += __shfl_xor(sv, off);
    }
    const float rk = 1.f / fmaxf(sqrtf(sk), 1e-12f);
    const float rv = 1.f / fmaxf(sqrtf(sv), 1e-12f);
    k2.x *= rk; k2.y *= rk;
    v2.x *= rv; v2.y *= rv;
    *(float2*)&Kb[base] = k2;
    *(float2*)&Vb[base] = v2;
    const unsigned short hx = f2b_rne(k2.x), hy = f2b_rne(k2.y);
    ((unsigned int*)K16)[base >> 1] = (unsigned int)hx | ((unsigned int)hy << 16);
    const unsigned short lx = f2b_rne(k2.x - b2f(hx));
    const unsigned short ly = f2b_rne(k2.y - b2f(hy));
    ((unsigned int*)K16lo)[base >> 1] = (unsigned int)lx | ((unsigned int)ly << 16);
}

// ---------------------------------------------------------------------------
// gram_kt: per (bh, c64-chunk): G = K_c K_c^T (f32, lo-compensated, MFMA) and
// K^T tiles (bf16 hi/lo) for the solve kernel's W-update GEMM.
// Grid: 32*32 = 1024 blocks, 256 threads. Fully parallel.
// ---------------------------------------------------------------------------
__global__ __launch_bounds__(256) void gram_kt(const unsigned short* __restrict__ K16,
                                               const unsigned short* __restrict__ K16lo,
                                               float* __restrict__ Gf,
                                               unsigned short* __restrict__ KThi,
                                               unsigned short* __restrict__ KTlo)
{
    __shared__ __align__(16) unsigned short Kp[2][64 * 136];   // [hi/lo][t][j] pad-136

    const int blk = blockIdx.x;
    const int c   = blk & 31;
    const int bh  = blk >> 5;
    const int b   = bh >> 3, h = bh & 7;
    const int tid = threadIdx.x;

    // stage K rows (plain, padded)
    {
        const int row = tid >> 2, seg = (tid & 3) * 32;
        const size_t gsrc = ((size_t)(b * Tlen + c * C64 + row)) * Dm + h * dh + seg;
        const s16x8* ph = (const s16x8*)&K16[gsrc];
        const s16x8* pl = (const s16x8*)&K16lo[gsrc];
#pragma unroll
        for (int q = 0; q < 4; ++q) {
            *(s16x8*)&Kp[0][row * 136 + seg + q * 8] = ph[q];
            *(s16x8*)&Kp[1][row * 136 + seg + q * 8] = pl[q];
        }
    }
    __syncthreads();

    const int w     = tid >> 6;
    const int lane  = tid & 63;
    const int row16 = lane & 15;
    const int quad  = lane >> 4;
    const int sh = (w >> 1) * 32;
    const int th = (w & 1) * 32;

    f32x4 ag[2][2];
#pragma unroll
    for (int i = 0; i < 2; ++i)
#pragma unroll
        for (int j = 0; j < 2; ++j)
            ag[2 > i ? i : i][j] = (f32x4){0.f, 0.f, 0.f, 0.f};

    // 3 passes: hi*hi + hi*lo + lo*hi
#pragma unroll
    for (int pass = 0; pass < 3; ++pass) {
        const int pa = (pass == 2) ? 1 : 0;
        const int pb = (pass == 1) ? 1 : 0;
#pragma unroll
        for (int k0 = 0; k0 < 128; k0 += 32) {
            s16x8 af[2], bf[2];
#pragma unroll
            for (int bm = 0; bm < 2; ++bm) {
                const int ml = sh + bm * 16 + row16;
                af[bm] = *(const s16x8*)&Kp[pa][ml * 136 + k0 + quad * 8];
            }
#pragma unroll
            for (int bn = 0; bn < 2; ++bn) {
                const int nl = th + bn * 16 + row16;
                bf[bn] = *(const s16x8*)&Kp[pb][nl * 136 + k0 + quad * 8];
            }
#pragma unroll
            for (int bm = 0; bm < 2; ++bm)
#pragma unroll
                for (int bn = 0; bn < 2; ++bn)
                    ag[bm][bn] = __builtin_amdgcn_mfma_f32_16x16x32_bf16(af[bm], bf[bn], ag[bm][bn], 0, 0, 0);
        }
    }

    // write G f32 [bh][c][s][t]
    float* gout = Gf + ((size_t)(bh * 32 + c)) * 4096;
#pragma unroll
    for (int bm = 0; bm < 2; ++bm)
#pragma unroll
        for (int bn = 0; bn < 2; ++bn) {
            const int t = th + bn * 16 + row16;
#pragma unroll
            for (int r = 0; r < 4; ++r) {
                const int s = sh + bm * 16 + quad * 4 + r;
                gout[s * 64 + t] = ag[bm][bn][r];
            }
        }

    // K^T extraction: KT[bh][c][j][t]
    {
        const int j   = tid >> 1;
        const int th2 = (tid & 1) * 32;
        unsigned int pk[16];
#pragma unroll
        for (int hl = 0; hl < 2; ++hl) {
#pragma unroll
            for (int p = 0; p < 16; ++p) {
                const unsigned short e0 = Kp[hl][(th2 + 2 * p) * 136 + j];
                const unsigned short e1 = Kp[hl][(th2 + 2 * p + 1) * 136 + j];
                pk[p] = (unsigned int)e0 | ((unsigned int)e1 << 16);
            }
            unsigned short* dst = (hl ? KTlo : KThi) +
                ((size_t)(bh * 32 + c) * 128 + j) * 64 + th2;
#pragma unroll
            for (int q = 0; q < 4; ++q)
                *(uint4*)&dst[q * 8] = *(uint4*)&pk[q * 4];
        }
    }
}

// ---------------------------------------------------------------------------
// solve_coef: the only serial kernel. One block per bh (32 blocks, 4 waves).
// Per 64-chunk: dump W (bf16)->LDS; A0 = W*K_c^T (MFMA) -> regs -> Khs (A0
// lives in Khs after P1b barrier: no aliasing with U buffers); blocked
// 64-step forward substitution (lane = i, 8x8 groups, COMPILE-TIME trip
// counts, f32x4 G rows batch-read from LDS); W += U*K_c (MFMA, compensated).
// Emits Ut / Wcp in the formats chunk_o consumes.  Dynamic LDS: 96 KiB.
// ---------------------------------------------------------------------------
__global__ __launch_bounds__(256) void solve_coef(const unsigned short* __restrict__ K16,
                                                  const float* __restrict__ Vb,
                                                  const float* __restrict__ LRb,
                                                  const float* __restrict__ Gf,
                                                  const unsigned short* __restrict__ KThi,
                                                  const unsigned short* __restrict__ KTlo,
                                                  unsigned short* __restrict__ Ut,
                                                  unsigned short* __restrict__ Wcp)
{
    extern __shared__ __align__(16) char smem[];
    unsigned short* Khs = (unsigned short*)smem;              // 16K: P0/P1 K (B-op); P1b+: A0
    unsigned short* Ws  = (unsigned short*)(smem + 16384);    // 32K: P0/P1 W slabs; P2/P3 KT slabs
    float*          Gs  = (float*)(smem + 49152);             // [64][64] f32 16K
    unsigned short* Uhi = (unsigned short*)(smem + 65536);    // [128][64] XOR 16K
    unsigned short* Ulo = (unsigned short*)(smem + 81920);    // [128][64] XOR 16K

    const int bh = blockIdx.x;
    const int b  = bh >> 3, h = bh & 7;
    const int tid   = threadIdx.x;
    const int w     = tid >> 6;
    const int lane  = tid & 63;
    const int p4    = lane & 3;
    const int row16 = lane & 15;
    const int quad  = lane >> 4;
    const int wm = (w >> 1) * 64;     // W-tile i-half
    const int wn = (w & 1) * 64;      // W-tile j-half
    const int ih  = (w >> 1) * 64;    // A0 i-half
    const int th2 = (w & 1) * 32;     // A0 t-half

    f32x4 Wa[4][4];
#pragma unroll
    for (int i = 0; i < 4; ++i)
#pragma unroll
        for (int j = 0; j < 4; ++j)
            Wa[i][j] = (f32x4){0.f, 0.f, 0.f, 0.f};

    const int ilane = w * 64 + lane;  // solve row (waves 0,1)

#pragma unroll 1
    for (int c = 0; c < NC64; ++c) {
        const int t0g = c * C64;

        // ---- P0: issue Khi + G stages; dump W -> Ws (bf16) --------------
#pragma unroll
        for (int c4 = 0; c4 < 4; ++c4) {
            const int rr = c4 * 16 + (lane >> 2);
            const unsigned short* ga = K16 + ((size_t)(b * Tlen + t0g + rr)) * Dm + h * dh
                                       + w * 32 + ((p4 ^ ((rr >> 1) & 3)) << 3);
            __builtin_amdgcn_global_load_lds(
                (const __attribute__((address_space(1))) void*)ga,
                (__attribute__((address_space(3))) void*)((char*)Khs + w * 4096 + c4 * 1024 + lane * 16),
                16, 0, 0);
        }
        {
            const size_t gbase = (size_t)(bh * 32 + c) * 4096;
#pragma unroll
            for (int c4 = 0; c4 < 4; ++c4) {
                const float* gg = Gf + gbase + w * 1024 + c4 * 256 + lane * 4;
                __builtin_amdgcn_global_load_lds(
                    (const __attribute__((address_space(1))) void*)gg,
                    (__attribute__((address_space(3))) void*)((char*)Gs + (w * 1024 + c4 * 256 + lane * 4) * 4),
                    16, 0, 0);
            }
        }
#pragma unroll
        for (int bm = 0; bm < 4; ++bm)
#pragma unroll
            for (int bn = 0; bn < 4; ++bn) {
                const int j  = wn + bn * 16 + row16;
                const int sl = j >> 5, jj = j & 31;
#pragma unroll
                for (int r = 0; r < 4; ++r) {
                    const int i = wm + bm * 16 + quad * 4 + r;
                    Ws[sl * 4096 + i * 32 + (((jj >> 3) ^ ((i >> 1) & 3)) << 3) + (j & 7)] =
                        f2b_rne(Wa[bm][bn][r]);
                }
            }
        __syncthreads();

        // ---- P1: A0 = W * K_c^T (MFMA) -> regs; checkpoint --------------
        f32x4 aA[4][2];
#pragma unroll
        for (int i = 0; i < 4; ++i)
#pragma unroll
            for (int j = 0; j < 2; ++j)
                aA[i][j] = (f32x4){0.f, 0.f, 0.f, 0.f};
#pragma unroll
        for (int k0s = 0; k0s < 4; ++k0s) {
            s16x8 af[4], bf[2];
#pragma unroll
            for (int bm = 0; bm < 4; ++bm) {
                const int ml = ih + bm * 16 + row16;
                af[bm] = *(const s16x8*)&Ws[k0s * 4096 + ml * 32 + ((quad ^ ((ml >> 1) & 3)) << 3)];
            }
#pragma unroll
            for (int bn = 0; bn < 2; ++bn) {
                const int nl = th2 + bn * 16 + row16;
                bf[bn] = *(const s16x8*)&Khs[k0s * 2048 + nl * 32 + ((quad ^ ((nl >> 1) & 3)) << 3)];
            }
#pragma unroll
            for (int bm = 0; bm < 4; ++bm)
#pragma unroll
                for (int bn = 0; bn < 2; ++bn)
                    aA[bm][bn] = __builtin_amdgcn_mfma_f32_16x16x32_bf16(af[bm], bf[bn], aA[bm][bn], 0, 0, 0);
        }
        // checkpoint copy (W at chunk start) every 2nd chunk: Ws -> Wcp
        if ((c & 1) == 0) {
            const int i2 = tid >> 1, half = tid & 1;
            unsigned short* dstrow = Wcp + ((size_t)(bh * NCH + (c >> 1)) * 128 + i2) * 128;
#pragma unroll
            for (int sl = 0; sl < 4; ++sl)
#pragma unroll
                for (int gq = 0; gq < 2; ++gq) {
                    const int gg = half * 2 + gq;
                    s16x8 v = *(const s16x8*)&Ws[sl * 4096 + i2 * 32 + ((gg ^ ((i2 >> 1) & 3)) << 3)];
                    *(s16x8*)&dstrow[sl * 32 + gg * 8] = v;
                }
        }
        __syncthreads();   // all Khs(K) and Ws(W) reads complete

        // ---- P1b: write A0 -> Khs ([t][i] XOR layout), all 4 waves ------
#pragma unroll
        for (int bm = 0; bm < 4; ++bm)
#pragma unroll
            for (int bn = 0; bn < 2; ++bn) {
                const int t = th2 + bn * 16 + row16;
#pragma unroll
                for (int r = 0; r < 4; ++r) {
                    const int i = ih + bm * 16 + quad * 4 + r;
                    Khs[t * 128 + (((i >> 3) ^ (t & 7)) << 3) + (i & 7)] = f2b_rne(aA[bm][bn][r]);
                }
            }
        __syncthreads();

        // ---- P2: waves 2,3: stage KT slabs into Ws; waves 0,1: solve ----
        if (w >= 2) {
            const int base2 = (w - 2) * 2;   // wave2: bufs 0,1 (hi); wave3: bufs 2,3 (lo)
#pragma unroll
            for (int bb = 0; bb < 2; ++bb) {
                const int buf = base2 + bb;
                const int st  = buf & 1;
                const unsigned short* src = (buf < 2) ? KThi : KTlo;
#pragma unroll
                for (int c8 = 0; c8 < 8; ++c8) {
                    const int jj = c8 * 16 + (lane >> 2);
                    const unsigned short* ga = src + ((size_t)(bh * 32 + c) * 128 + jj) * 64
                                               + st * 32 + ((p4 ^ ((jj >> 1) & 3)) << 3);
                    __builtin_amdgcn_global_load_lds(
                        (const __attribute__((address_space(1))) void*)ga,
                        (__attribute__((address_space(3))) void*)((char*)Ws + buf * 8192 + c8 * 1024 + lane * 16),
                        16, 0, 0);
                }
            }
        } else {
            const int i = ilane;
            const float* vp  = Vb  + ((size_t)(b * Tlen + t0g)) * Dm + h * dh + i;
            const float* lrp = LRb + ((size_t)(b * Tlen + t0g)) * Dm + h * dh + i;
            // r-init: r4[q][e] = v[t] - A0[t][i],  t = 4q+e
            f32x4 r4[16];
#pragma unroll
            for (int q = 0; q < 16; ++q) {
#pragma unroll
                for (int e = 0; e < 4; ++e) {
                    const int t = 4 * q + e;
                    const float a0 = b2f(Khs[t * 128 + (((i >> 3) ^ (t & 7)) << 3) + (i & 7)]);
                    r4[q][e] = vp[(size_t)t * Dm] - a0;
                }
            }
            float lv[8], o8[8];
#pragma unroll
            for (int g = 0; g < 8; ++g) {
#pragma unroll
                for (int u = 0; u < 8; ++u)
                    lv[u] = lrp[(size_t)(g * 8 + u) * Dm];
#pragma unroll
                for (int su = 0; su < 8; ++su) {
                    const int s = g * 8 + su;
                    const float cf = lv[su] * r4[s >> 2][s & 3];   // static idx (unrolled)
                    o8[su] = cf;
                    const f32x4 cf4 = (f32x4){cf, cf, cf, cf};
                    // compile-time trip: quads 2g..15 (earlier quads are consumed/dead)
#pragma unroll
                    for (int q = 2 * g; q < 16; ++q) {
                        const f32x4 g4 = *(const f32x4*)&Gs[s * 64 + q * 4];
                        r4[q] -= cf4 * g4;
                    }
                }
                // pack & store U for this group (t0 = 8g)
                unsigned int phi[4], plo[4];
#pragma unroll
                for (int qq = 0; qq < 4; ++qq) {
                    const unsigned short h0 = f2b_rne(o8[2 * qq]);
                    const unsigned short h1 = f2b_rne(o8[2 * qq + 1]);
                    const unsigned short l0 = f2b_rne(o8[2 * qq] - b2f(h0));
                    const unsigned short l1 = f2b_rne(o8[2 * qq + 1] - b2f(h1));
                    phi[qq] = (unsigned int)h0 | ((unsigned int)h1 << 16);
                    plo[qq] = (unsigned int)l0 | ((unsigned int)l1 << 16);
                }
                const int lg = g ^ (i & 7);
                *(uint4*)&Uhi[i * 64 + (lg << 3)] = *(uint4*)phi;
                *(uint4*)&Ulo[i * 64 + (lg << 3)] = *(uint4*)plo;
                *(uint4*)&Ut[(size_t)(bh * 128 + i) * Tlen + t0g + 8 * g] = *(uint4*)phi;
            }
        }
        __syncthreads();

        // ---- P3: W += Uhi*KThi + Ulo*KThi + Uhi*KTlo (MFMA) -------------
#pragma unroll
        for (int pass = 0; pass < 3; ++pass) {
            const unsigned short* Ua = (pass == 1) ? Ulo : Uhi;
            const int bufbase = (pass == 2) ? 2 : 0;
#pragma unroll
            for (int st = 0; st < 2; ++st) {
                s16x8 af[4], bf[4];
#pragma unroll
                for (int bm = 0; bm < 4; ++bm) {
                    const int ml = wm + bm * 16 + row16;
                    af[bm] = *(const s16x8*)&Ua[ml * 64 + (((st * 4 + quad) ^ (ml & 7)) << 3)];
                }
#pragma unroll
                for (int bn = 0; bn < 4; ++bn) {
                    const int nl = wn + bn * 16 + row16;
                    bf[bn] = *(const s16x8*)&Ws[(bufbase + st) * 4096 + nl * 32 + ((quad ^ ((nl >> 1) & 3)) << 3)];
                }
#pragma unroll
                for (int bm = 0; bm < 4; ++bm)
#pragma unroll
                    for (int bn = 0; bn < 4; ++bn)
                        Wa[bm][bn] = __builtin_amdgcn_mfma_f32_16x16x32_bf16(af[bm], bf[bn], Wa[bm][bn], 0, 0, 0);
            }
        }
        __syncthreads();
    }
}

// ---------------------------------------------------------------------------
// Pass 2: per 128-chunk output via MFMA.  (unchanged, proven)
// ---------------------------------------------------------------------------
__global__ __launch_bounds__(256) void chunk_o(const unsigned short* __restrict__ Q16,
                                               const unsigned short* __restrict__ K16,
                                               const unsigned short* __restrict__ Ut,
                                               const unsigned short* __restrict__ Wcp,
                                               unsigned short* __restrict__ Obb)
{
    __shared__ __align__(16) unsigned short As[128 * 32];
    __shared__ __align__(16) unsigned short Bs[128 * 32];
    __shared__ __align__(16) unsigned short Sb[128 * 136];   // +8 pad

    const int blk = blockIdx.x;
    const int c   = blk & (NCH - 1);
    const int bh  = blk >> 4;
    const int b   = bh >> 3, h = bh & 7;

    const int tid   = threadIdx.x;
    const int w     = tid >> 6;
    const int lane  = tid & 63;
    const int r4    = lane >> 2;
    const int p4    = lane & 3;
    const int row16 = lane & 15;
    const int quad  = lane >> 4;
    const int wm = (w >> 1) * 64;
    const int wn = (w & 1) * 64;

    const size_t qkbase = (size_t)b * Tlen * Dm + (size_t)(c * CH) * Dm + (size_t)h * dh;
    const size_t ubase  = (size_t)bh * dh * Tlen + (size_t)c * CH;
    const size_t wbase  = ((size_t)bh * NCH + c) * dh * dh;

    f32x4 acc[4][4];
#pragma unroll
    for (int i = 0; i < 4; ++i)
#pragma unroll
        for (int j = 0; j < 4; ++j)
            acc[i][j] = (f32x4){0.f, 0.f, 0.f, 0.f};

    for (int k0 = 0; k0 < 128; k0 += 32) {
        __syncthreads();
#pragma unroll
        for (int cc = 0; cc < 2; ++cc) {
            const int ml  = w * 32 + cc * 16 + r4;
            const int swz = (ml >> 1) & 3;
            const unsigned short* ga = Q16 + qkbase + (size_t)ml * Dm + k0 + ((p4 ^ swz) << 3);
            const unsigned short* gb = K16 + qkbase + (size_t)ml * Dm + k0 + ((p4 ^ swz) << 3);
            __builtin_amdgcn_global_load_lds(
                (const __attribute__((address_space(1))) void*)ga,
                (__attribute__((address_space(3))) void*)&As[(w * 32 + cc * 16) * 32], 16, 0, 0);
            __builtin_amdgcn_global_load_lds(
                (const __attribute__((address_space(1))) void*)gb,
                (__attribute__((address_space(3))) void*)&Bs[(w * 32 + cc * 16) * 32], 16, 0, 0);
        }
        __syncthreads();

        s16x8 af[4], bf[4];
#pragma unroll
        for (int bm = 0; bm < 4; ++bm) {
            const int ml  = wm + bm * 16 + row16;
            const int pos = quad ^ ((ml >> 1) & 3);
            af[bm] = *(const s16x8*)&As[ml * 32 + pos * 8];
        }
#pragma unroll
        for (int bn = 0; bn < 4; ++bn) {
            const int nl  = wn + bn * 16 + row16;
            const int pos = quad ^ ((nl >> 1) & 3);
            bf[bn] = *(const s16x8*)&Bs[nl * 32 + pos * 8];
        }
#pragma unroll
        for (int bm = 0; bm < 4; ++bm)
#pragma unroll
            for (int bn = 0; bn < 4; ++bn)
                acc[bm][bn] = __builtin_amdgcn_mfma_f32_16x16x32_bf16(af[bm], bf[bn], acc[bm][bn], 0, 0, 0);
    }

#pragma unroll
    for (int bm = 0; bm < 4; ++bm) {
#pragma unroll
        for (int bn = 0; bn < 4; ++bn) {
            const int s_loc = wn + bn * 16 + row16;
#pragma unroll
            for (int r = 0; r < 4; ++r) {
                const int t_loc = wm + bm * 16 + quad * 4 + r;
                const float val = (s_loc <= t_loc) ? acc[bm][bn][r] : 0.f;
                Sb[t_loc * 136 + s_loc] = f2b_rne(val);
            }
            acc[bm][bn] = (f32x4){0.f, 0.f, 0.f, 0.f};
        }
    }

    for (int k0 = 0; k0 < 128; k0 += 32) {
        __syncthreads();
#pragma unroll
        for (int cc = 0; cc < 2; ++cc) {
            const int nl  = w * 32 + cc * 16 + r4;
            const int swz = (nl >> 1) & 3;
            const unsigned short* gb = Ut + ubase + (size_t)nl * Tlen + k0 + ((p4 ^ swz) << 3);
            __builtin_amdgcn_global_load_lds(
                (const __attribute__((address_space(1))) void*)gb,
                (__attribute__((address_space(3))) void*)&Bs[(w * 32 + cc * 16) * 32], 16, 0, 0);
        }
        __syncthreads();

        s16x8 af[4], bf[4];
#pragma unroll
        for (int bm = 0; bm < 4; ++bm) {
            const int ml = wm + bm * 16 + row16;
            af[bm] = *(const s16x8*)&Sb[ml * 136 + k0 + quad * 8];
        }
#pragma unroll
        for (int bn = 0; bn < 4; ++bn) {
            const int nl  = wn + bn * 16 + row16;
            const int pos = quad ^ ((nl >> 1) & 3);
            bf[bn] = *(const s16x8*)&Bs[nl * 32 + pos * 8];
        }
#pragma unroll
        for (int bm = 0; bm < 4; ++bm)
#pragma unroll
            for (int bn = 0; bn < 4; ++bn)
                acc[bm][bn] = __builtin_amdgcn_mfma_f32_16x16x32_bf16(af[bm], bf[bn], acc[bm][bn], 0, 0, 0);
    }

    for (int k0 = 0; k0 < 128; k0 += 32) {
        __syncthreads();
#pragma unroll
        for (int cc = 0; cc < 2; ++cc) {
            const int ml  = w * 32 + cc * 16 + r4;
            const int swz = (ml >> 1) & 3;
            const unsigned short* ga = Q16 + qkbase + (size_t)ml * Dm + k0 + ((p4 ^ swz) << 3);
            const unsigned short* gb = Wcp + wbase + (size_t)ml * dh + k0 + ((p4 ^ swz) << 3);
            __builtin_amdgcn_global_load_lds(
                (const __attribute__((address_space(1))) void*)ga,
                (__attribute__((address_space(3))) void*)&As[(w * 32 + cc * 16) * 32], 16, 0, 0);
            __builtin_amdgcn_global_load_lds(
                (const __attribute__((address_space(1))) void*)gb,
                (__attribute__((address_space(3))) void*)&Bs[(w * 32 + cc * 16) * 32], 16, 0, 0);
        }
        __syncthreads();

        s16x8 af[4], bf[4];
#pragma unroll
        for (int bm = 0; bm < 4; ++bm) {
            const int ml  = wm + bm * 16 + row16;
            const int pos = quad ^ ((ml >> 1) & 3);
            af[bm] = *(const s16x8*)&As[ml * 32 + pos * 8];
        }
#pragma unroll
        for (int bn = 0; bn < 4; ++bn) {
            const int nl  = wn + bn * 16 + row16;
            const int pos = quad ^ ((nl >> 1) & 3);
            bf[bn] = *(const s16x8*)&Bs[nl * 32 + pos * 8];
        }
#pragma unroll
        for (int bm = 0; bm < 4; ++bm)
#pragma unroll
            for (int bn = 0; bn < 4; ++bn)
                acc[bm][bn] = __builtin_amdgcn_mfma_f32_16x16x32_bf16(af[bm], bf[bn], acc[bm][bn], 0, 0, 0);
    }

#pragma unroll
    for (int bm = 0; bm < 4; ++bm) {
#pragma unroll
        for (int bn = 0; bn < 4; ++bn) {
            const int i_loc = wn + bn * 16 + row16;
#pragma unroll
            for (int r = 0; r < 4; ++r) {
                const int t_loc = wm + bm * 16 + quad * 4 + r;
                Obb[qkbase + (size_t)t_loc * Dm + i_loc] = f2b_rne(acc[bm][bn][r]);
            }
        }
    }
}

// ---------------------------------------------------------------------------
extern "C" void kernel_launch(void* const* d_in, const int* in_sizes, int n_in,
                              void* d_out, int out_size, void* d_ws, size_t ws_size,
                              hipStream_t stream)
{
    const float* x    = (const float*)d_in[0];
    const float* Wq   = (const float*)d_in[1];
    const float* Wk   = (const float*)d_in[2];
    const float* Wv   = (const float*)d_in[3];
    const float* Wo   = (const float*)d_in[4];
    const float* Wlr  = (const float*)d_in[5];
    const float* b_lr = (const float*)d_in[6];

    float* ws = (float*)d_ws;
    const size_t S  = (size_t)Mrows * Dm;    // 8388608
    const size_t SW = (size_t)Dm * Dm;       // 1048576
    float* Kb  = ws;
    float* Vb  = ws + S;
    float* LRb = ws + 2 * S;
    unsigned short* xb   = (unsigned short*)(ws + 3 * S);  // S bf16
    unsigned short* Wcp  = xb;                             // alias: xb dead before solve
    unsigned short* Q16  = xb + S;
    unsigned short* K16  = Q16 + S;
    unsigned short* Ut   = K16 + S;
    unsigned short* Obb  = Ut + S;
    unsigned short* Wqb  = Obb + S;
    unsigned short* Wkb  = Wqb + SW;
    unsigned short* Wvb  = Wkb + SW;
    unsigned short* Wlrb = Wvb + SW;
    unsigned short* Wob  = Wlrb + SW;
    // lifetime-disjoint aliases for the new pipeline:
    unsigned short* K16lo = Ut;              // l2norm -> gram window (Ut written later by solve)
    float*          Gf    = (float*)Obb;     // gram -> solve window (Obb written later by chunk_o)
    unsigned short* KThi  = (unsigned short*)Kb;  // gram -> solve window (Kb f32 dead after l2norm)
    unsigned short* KTlo  = KThi + S;        // KThi+KTlo = exactly |Kb|

    static int attr_done = 0;
    if (!attr_done) {
        (void)hipFuncSetAttribute((const void*)solve_coef,
                                  hipFuncAttributeMaxDynamicSharedMemorySize, 98304);
        attr_done = 1;
    }

    cvt_f32_bf16<<<S / 1024, 256, 0, stream>>>(x, xb);
    cvt_f32_bf16<<<SW / 1024, 256, 0, stream>>>(Wq, Wqb);
    cvt_f32_bf16<<<SW / 1024, 256, 0, stream>>>(Wk, Wkb);
    cvt_f32_bf16<<<SW / 1024, 256, 0, stream>>>(Wv, Wvb);
    cvt_f32_bf16<<<SW / 1024, 256, 0, stream>>>(Wlr, Wlrb);
    cvt_f32_bf16<<<SW / 1024, 256, 0, stream>>>(Wo, Wob);

    dim3 gg(Dm / 128, Mrows / 128);
    gemm_bf16<<<gg, 256, 0, stream>>>(xb, Wqb, nullptr, nullptr, Q16, 2);
    gemm_bf16<<<gg, 256, 0, stream>>>(xb, Wkb, nullptr, Kb, nullptr, 0);
    gemm_bf16<<<gg, 256, 0, stream>>>(xb, Wvb, nullptr, Vb, nullptr, 0);
    gemm_bf16<<<gg, 256, 0, stream>>>(xb, Wlrb, b_lr, LRb, nullptr, 1);

    l2norm_rows<<<(Bsz * Tlen * Hh) / 4, 256, 0, stream>>>(Kb, Vb, K16, K16lo);

    gram_kt<<<32 * 32, 256, 0, stream>>>(K16, K16lo, Gf, KThi, KTlo);

    solve_coef<<<32, 256, 98304, stream>>>(K16, Vb, LRb, Gf, KThi, KTlo, Ut, Wcp);

    chunk_o<<<Bsz * Hh * NCH, 256, 0, stream>>>(Q16, K16, Ut, Wcp, Obb);

    gemm_bf16<<<gg, 256, 0, stream>>>(Obb, Wob, nullptr, (float*)d_out, nullptr, 0);
}